// Round 7
// baseline (287.078 us; speedup 1.0000x reference)
//
#include <hip/hip_runtime.h>

#define EMBED 1024
#define SEQ   2048
#define BATCH 4
#define HEADS 16

typedef __attribute__((ext_vector_type(8))) short short8;   // 8 bf16 in 4 VGPRs
typedef __attribute__((ext_vector_type(4))) float floatx4;
typedef __attribute__((ext_vector_type(16))) float floatx16;

#define MFMA16(a, b, c) __builtin_amdgcn_mfma_f32_16x16x32_bf16((a), (b), (c), 0, 0, 0)
#define MFMA32(a, b, c) __builtin_amdgcn_mfma_f32_32x32x16_bf16((a), (b), (c), 0, 0, 0)
#define ATT_SCALE (0.125f * 1.44269504088896340736f)   // 1/sqrt(64) * log2(e), folded into Q

static __device__ __forceinline__ unsigned short f2bf(float f) {
  union { float f; unsigned int u; } v; v.f = f;
  unsigned int u = v.u;
  u += 0x7fffu + ((u >> 16) & 1u);       // RNE
  return (unsigned short)(u >> 16);
}

// v_cvt_pk_bf16_f32: dst.lo16 = bf16(lo), dst.hi16 = bf16(hi)  (RNE)
static __device__ __forceinline__ unsigned cvtpk(float lo, float hi) {
  unsigned r;
  asm("v_cvt_pk_bf16_f32 %0, %1, %2" : "=v"(r) : "v"(lo), "v"(hi));
  return r;
}

static __device__ __forceinline__ void async16(const unsigned short* g, unsigned short* l) {
  __builtin_amdgcn_global_load_lds(
      (const __attribute__((address_space(1))) void*)g,
      (__attribute__((address_space(3))) void*)l, 16, 0, 0);
}

// ---------------- fused prep: hidden fp32->bf16 (blocks 0..4095) +
//                  W[k][n]->WT[n][k] bf16 for Wq,Wk,Wv,Wp (blocks 4096..5119) ---
__global__ __launch_bounds__(256) void k_prep(const float* __restrict__ hid,
                                              unsigned short* __restrict__ hidA,
                                              const float* __restrict__ Wq, const float* __restrict__ Wk,
                                              const float* __restrict__ Wv, const float* __restrict__ Wp,
                                              unsigned short* __restrict__ WT) {
  __shared__ unsigned short tile[64][65];
  const int bid = blockIdx.x, tid = threadIdx.x;
  if (bid < 4096) {                       // cvt: 8 floats / thread
    int i = bid * 256 + tid;
    const float4* s = (const float4*)hid;
    float4 a = s[i * 2], b = s[i * 2 + 1];
    uint4 o;
    o.x = (unsigned)f2bf(a.x) | ((unsigned)f2bf(a.y) << 16);
    o.y = (unsigned)f2bf(a.z) | ((unsigned)f2bf(a.w) << 16);
    o.z = (unsigned)f2bf(b.x) | ((unsigned)f2bf(b.y) << 16);
    o.w = (unsigned)f2bf(b.z) | ((unsigned)f2bf(b.w) << 16);
    ((uint4*)hidA)[i] = o;
    return;
  }
  const int idx = bid - 4096;
  const int z = idx >> 8, rem = idx & 255;
  const float* src = (z == 0) ? Wq : (z == 1) ? Wk : (z == 2) ? Wv : Wp;
  unsigned short* dst = WT + (size_t)z * EMBED * EMBED;
  const int k0 = (rem & 15) * 64, n0 = (rem >> 4) * 64;
  for (int i = tid; i < 4096; i += 256) {
    int r = i >> 6, c = i & 63;
    tile[c][r] = f2bf(src[(size_t)(k0 + r) * EMBED + n0 + c]);
  }
  __syncthreads();
  for (int i = tid; i < 4096; i += 256) {
    int r = i >> 6, c = i & 63;
    dst[(size_t)(n0 + r) * EMBED + k0 + c] = tile[r][c];
  }
}

// ---------------- QKV GEMM (128x128, proven structure) + fused V-transpose ----
// by < 16 : C[m][n0..] = hidA[m,:].WT_qk[n,:] + bias  (Q cols pre-scaled)
// by >= 16: V^T by operand symmetry (rows = d, cols = l); writes VT directly.
__global__ __launch_bounds__(256) void k_gemm_qkv(const unsigned short* __restrict__ A,
                                                  const unsigned short* __restrict__ BT,
                                                  const float* __restrict__ bq,
                                                  const float* __restrict__ bk,
                                                  const float* __restrict__ bv,
                                                  unsigned short* __restrict__ C,
                                                  unsigned short* __restrict__ VT) {
  __shared__ unsigned short Als[128 * 64];
  __shared__ unsigned short Bls[128 * 64];
  const int tid = threadIdx.x;
  const int by = blockIdx.y;
  const bool vmode = (by >= 16);
  const int arow0 = vmode ? (by - 16) * 128 : blockIdx.x * 128;
  const int brow0 = vmode ? blockIdx.x * 128 : by * 128;
  const int w = tid >> 6, lane = tid & 63, l16 = lane & 15, quad = lane >> 4;
  const int l7 = l16 & 7;
  const int wrow = (w >> 1) * 64, wcol = (w & 1) * 64;

  floatx4 acc[4][4];
#pragma unroll
  for (int i = 0; i < 4; ++i)
#pragma unroll
    for (int j = 0; j < 4; ++j) acc[i][j] = {0.f, 0.f, 0.f, 0.f};

  const int srow = tid >> 3;
  const int scol = (((tid & 7) ^ (srow & 7)) * 8);
  const unsigned short* Arow = vmode ? (BT + (size_t)2 * EMBED * EMBED) : A;
  const unsigned short* Brow = vmode ? A : BT;
  const unsigned short* Ap = Arow + (size_t)(arow0 + srow) * EMBED + scol;
  const unsigned short* Bp = Brow + (size_t)(brow0 + srow) * EMBED + scol;

  int ab[2], bb[2];
#pragma unroll
  for (int kc = 0; kc < 2; ++kc) {
    ab[kc] = (wrow + l16) * 64 + (((4 * kc + quad) ^ l7) << 3);
    bb[kc] = (wcol + l16) * 64 + (((4 * kc + quad) ^ l7) << 3);
  }

  for (int kt = 0; kt < 16; ++kt) {
    const int k0 = kt * 64;
#pragma unroll
    for (int i = 0; i < 4; ++i)
      async16(Ap + k0 + (size_t)i * 32 * EMBED, Als + i * 2048 + tid * 8);
#pragma unroll
    for (int i = 0; i < 4; ++i)
      async16(Bp + k0 + (size_t)i * 32 * EMBED, Bls + i * 2048 + tid * 8);
    __syncthreads();
    short8 af[4][2], bf[4][2];
#pragma unroll
    for (int mt = 0; mt < 4; ++mt)
#pragma unroll
      for (int kc = 0; kc < 2; ++kc)
        af[mt][kc] = *(const short8*)(Als + ab[kc] + mt * 1024);
#pragma unroll
    for (int nt = 0; nt < 4; ++nt)
#pragma unroll
      for (int kc = 0; kc < 2; ++kc)
        bf[nt][kc] = *(const short8*)(Bls + bb[kc] + nt * 1024);
#pragma unroll
    for (int kc = 0; kc < 2; ++kc)
#pragma unroll
      for (int mt = 0; mt < 4; ++mt)
#pragma unroll
        for (int nt = 0; nt < 4; ++nt)
          acc[mt][nt] = MFMA16(af[mt][kc], bf[nt][kc], acc[mt][nt]);
    __syncthreads();
  }

  if (!vmode) {
    const int n0 = brow0;
    const float* bsel = (n0 < 1024) ? bq : bk;
    const float scl = (n0 < 1024) ? ATT_SCALE : 1.0f;
    const int nb = n0 & 1023;
    float bias[4];
#pragma unroll
    for (int nt = 0; nt < 4; ++nt) bias[nt] = bsel[nb + wcol + nt * 16 + l16];
#pragma unroll
    for (int mt = 0; mt < 4; ++mt)
#pragma unroll
      for (int r = 0; r < 4; ++r) {
        int gm = arow0 + wrow + mt * 16 + quad * 4 + r;
        size_t base = (size_t)gm * 3072 + n0 + wcol;
#pragma unroll
        for (int nt = 0; nt < 4; ++nt)
          C[base + nt * 16 + l16] = f2bf((acc[mt][nt][r] + bias[nt]) * scl);
      }
  } else {
    // rows = d-global, cols = l-global; VT[(b*16+h)*64 + d][l]
#pragma unroll
    for (int mt = 0; mt < 4; ++mt)
#pragma unroll
      for (int r = 0; r < 4; ++r) {
        const int drow = arow0 + wrow + mt * 16 + quad * 4 + r;   // 0..1023
        const float bias = bv[drow];
        const int cg0 = brow0 + wcol;                             // col base (l-global)
        const int b = cg0 >> 11;                                  // constant per block
        const size_t base = ((size_t)((b * 16 + (drow >> 6)) * 64 + (drow & 63))) * SEQ
                            + (cg0 & 2047);
#pragma unroll
        for (int nt = 0; nt < 4; ++nt)
          VT[base + nt * 16 + l16] = f2bf(acc[mt][nt][r] + bias);
      }
  }
}

// ---------------- attention v13: v10 math, 2-wave drift blocks ----------------
// Same per-wave work as v10 (64 q-rows — R4 taught: don't shrink wave work).
// Block = 128 threads (2 waves), grid (64,16) = 1024 blocks -> 4 INDEPENDENT
// blocks/CU instead of 2.  R6 counters: VALU 47 + MFMA 37, neither saturated —
// 4-wave lockstep aligned all waves into the same phase (exp2 together, MFMA
// together).  Smaller drift units give 4 phase-independent streams per CU so
// VALU of one block overlaps MFMA of another (m114 mechanism).  Barriers are
// now pairwise.  Cost: 8 async16/thread/kt (staging per block halved in
// threads), 2x K/V L2 re-read (~8 TB/s, far under 34.5 ceiling).
__global__ __launch_bounds__(128, 2) void k_attn(const unsigned short* __restrict__ QKV,
                                                 const unsigned short* __restrict__ VT,
                                                 unsigned short* __restrict__ CTX) {
  const int bh = blockIdx.x, qt = blockIdx.y;
  const int b = bh >> 4, h = bh & 15;
  const int tid = threadIdx.x;
  const int w = tid >> 6, lane = tid & 63;
  const int l32 = lane & 31, hi = lane >> 5;

  __shared__ unsigned short Kls[2][64 * 64];   // [buf][kv][d]  xor-chunk swizzled
  __shared__ unsigned short Vls[2][64 * 64];   // [buf][d][kv]  xor-chunk swizzled
  __shared__ float rsls[2][64];                // per-wave row sums

  const unsigned short* Qb = QKV + (size_t)(b * SEQ + qt * 128 + w * 64) * 3072 + h * 64;
  const unsigned short* Kb = QKV + (size_t)(b * SEQ) * 3072 + 1024 + h * 64;
  const unsigned short* Vb = VT + (size_t)bh * 64 * SEQ;

  // Q fragments (B-operand of swapped QK): qf[qg][ds] holds
  // Q[q = qg*32 + l32][d = ds*16 + hi*8 + j]  (pre-scaled by ATT_SCALE)
  short8 qf[2][4];
#pragma unroll
  for (int qg = 0; qg < 2; ++qg)
#pragma unroll
    for (int ds = 0; ds < 4; ++ds)
      qf[qg][ds] = *(const short8*)(Qb + (size_t)(qg * 32 + l32) * 3072 + ds * 16 + hi * 8);

  floatx16 o[2][2];
  float rs[2] = {0.f, 0.f};
#pragma unroll
  for (int qg = 0; qg < 2; ++qg)
#pragma unroll
    for (int dg = 0; dg < 2; ++dg)
#pragma unroll
      for (int c = 0; c < 16; ++c) o[qg][dg][c] = 0.f;

  // staging: 128 threads, srow 0..15, 4 row-groups of 16 cover 64 rows
  const int srow = tid >> 3;                              // 0..15
  const int scol = (((tid & 7) ^ (srow & 7)) * 8);        // swizzled source chunk
  // row-group stride 16 keeps (row&7) == (srow&7), so read-side xor matches

  // prologue: stage kt=0 into buf 0
#pragma unroll
  for (int g = 0; g < 4; ++g)
    async16(Kb + (size_t)(g * 16 + srow) * 3072 + scol, Kls[0] + g * 1024 + tid * 8);
#pragma unroll
  for (int g = 0; g < 4; ++g)
    async16(Vb + (size_t)(g * 16 + srow) * SEQ + scol, Vls[0] + g * 1024 + tid * 8);
  __syncthreads();

  int cur = 0;
  for (int kt = 0; kt < 32; ++kt) {
    if (kt < 31) {                          // prefetch kt+1 into buf^1
      const int kn = (kt + 1) * 64;
      unsigned short* Kd = Kls[cur ^ 1];
      unsigned short* Vd = Vls[cur ^ 1];
#pragma unroll
      for (int g = 0; g < 4; ++g)
        async16(Kb + (size_t)(kn + g * 16 + srow) * 3072 + scol, Kd + g * 1024 + tid * 8);
#pragma unroll
      for (int g = 0; g < 4; ++g)
        async16(Vb + (size_t)(g * 16 + srow) * SEQ + kn + scol, Vd + g * 1024 + tid * 8);
    }
    const unsigned short* Kc = Kls[cur];
    const unsigned short* Vc = Vls[cur];

    short8 pa[2][4];   // [qg][ks] packed P fragments (PV A-operand)
#pragma unroll
    for (int kvg = 0; kvg < 2; ++kvg) {
      short8 kf[4];    // K A-frags: lane = kv-row kvg*32+l32, k = d-chunk
#pragma unroll
      for (int ds = 0; ds < 4; ++ds) {
        const int row = kvg * 32 + l32;
        kf[ds] = *(const short8*)(Kc + row * 64 + (((ds * 2 + hi) ^ (row & 7)) << 3));
      }
#pragma unroll
      for (int qg = 0; qg < 2; ++qg) {
        floatx16 s;
#pragma unroll
        for (int c = 0; c < 16; ++c) s[c] = 0.f;
#pragma unroll
        for (int ds = 0; ds < 4; ++ds) s = MFMA32(kf[ds], qf[qg][ds], s);
        float p[16];
#pragma unroll
        for (int c = 0; c < 16; ++c) p[c] = __builtin_amdgcn_exp2f(s[c]);
        rs[qg] += (((p[0] + p[1]) + (p[2] + p[3])) + ((p[4] + p[5]) + (p[6] + p[7])))
                + (((p[8] + p[9]) + (p[10] + p[11])) + ((p[12] + p[13]) + (p[14] + p[15])));
#pragma unroll
        for (int half = 0; half < 2; ++half) {   // ks = kvg*2 + half
          unsigned w0 = cvtpk(p[half * 8 + 0], p[half * 8 + 1]);
          unsigned w1 = cvtpk(p[half * 8 + 2], p[half * 8 + 3]);
          unsigned w2 = cvtpk(p[half * 8 + 4], p[half * 8 + 5]);
          unsigned w3 = cvtpk(p[half * 8 + 6], p[half * 8 + 7]);
          asm("v_permlane32_swap_b32 %0, %1" : "+v"(w0), "+v"(w2));
          asm("v_permlane32_swap_b32 %0, %1" : "+v"(w1), "+v"(w3));
          union { unsigned u[4]; short8 s8; } pk;
          pk.u[0] = w0; pk.u[1] = w1; pk.u[2] = w2; pk.u[3] = w3;
          pa[qg][kvg * 2 + half] = pk.s8;
        }
      }
    }

    // O += P V   (V B-frags: lane = d-col dg*32+l32, k = kv-chunk)
#pragma unroll
    for (int dg = 0; dg < 2; ++dg) {
      short8 vf[4];
#pragma unroll
      for (int ks = 0; ks < 4; ++ks) {
        const int row = dg * 32 + l32;
        vf[ks] = *(const short8*)(Vc + row * 64 + (((ks * 2 + hi) ^ (row & 7)) << 3));
      }
#pragma unroll
      for (int qg = 0; qg < 2; ++qg)
#pragma unroll
        for (int ks = 0; ks < 4; ++ks)
          o[qg][dg] = MFMA32(pa[qg][ks], vf[ks], o[qg][dg]);
    }

    // single pairwise barrier: drains the prefetch after compute hid its
    // latency, and protects buf[cur^1] before kt+1 overwrites it
    __syncthreads();
    cur ^= 1;
  }

  // lanes l and l+32 hold the same q; combine, publish per-q sums via LDS
  rs[0] += __shfl_xor(rs[0], 32);
  rs[1] += __shfl_xor(rs[1], 32);
  if (lane < 32) {
    rsls[w][l32] = rs[0];
    rsls[w][32 + l32] = rs[1];
  }
  // same-wave LDS readback; per-wave in-order, compiler inserts the lgkm wait

  // write ctx[b*SEQ + q][h*64 + d] bf16; O rows: q = (j&3)+8*(j>>2)+4*hi (+32qg)
#pragma unroll
  for (int qg = 0; qg < 2; ++qg)
#pragma unroll
    for (int j = 0; j < 16; ++j) {
      const int rl = (j & 3) + 8 * (j >> 2) + 4 * hi;
      const float inv = 1.f / rsls[w][qg * 32 + rl];
      const int gq = b * SEQ + qt * 128 + w * 64 + qg * 32 + rl;
      const size_t base = (size_t)gq * EMBED + h * 64;
#pragma unroll
      for (int dg = 0; dg < 2; ++dg)
        CTX[base + dg * 32 + l32] = f2bf(o[qg][dg][j] * inv);
    }
}

// ---------------- proj GEMM + bias + residual -> fp32 x ----------------
__global__ __launch_bounds__(256) void k_gemm_proj(const unsigned short* __restrict__ A,
                                                   const unsigned short* __restrict__ BT,
                                                   const float* __restrict__ bp,
                                                   const float* __restrict__ hid,
                                                   float* __restrict__ X) {
  __shared__ unsigned short Als[128 * 64];
  __shared__ unsigned short Bls[128 * 64];
  const int tid = threadIdx.x;
  const int m0 = blockIdx.x * 128, n0 = blockIdx.y * 128;
  const int w = tid >> 6, lane = tid & 63, l16 = lane & 15, quad = lane >> 4;
  const int l7 = l16 & 7;
  const int wrow = (w >> 1) * 64, wcol = (w & 1) * 64;

  floatx4 acc[4][4];
#pragma unroll
  for (int i = 0; i < 4; ++i)
#pragma unroll
    for (int j = 0; j < 4; ++j) acc[i][j] = {0.f, 0.f, 0.f, 0.f};

  const int srow = tid >> 3;
  const int scol = (((tid & 7) ^ (srow & 7)) * 8);
  const unsigned short* Ap = A + (size_t)(m0 + srow) * EMBED + scol;
  const unsigned short* Bp = BT + (size_t)(n0 + srow) * EMBED + scol;

  int ab[2], bb[2];
#pragma unroll
  for (int kc = 0; kc < 2; ++kc) {
    ab[kc] = (wrow + l16) * 64 + (((4 * kc + quad) ^ l7) << 3);
    bb[kc] = (wcol + l16) * 64 + (((4 * kc + quad) ^ l7) << 3);
  }

  for (int kt = 0; kt < 16; ++kt) {
    const int k0 = kt * 64;
#pragma unroll
    for (int i = 0; i < 4; ++i)
      async16(Ap + k0 + (size_t)i * 32 * EMBED, Als + i * 2048 + tid * 8);
#pragma unroll
    for (int i = 0; i < 4; ++i)
      async16(Bp + k0 + (size_t)i * 32 * EMBED, Bls + i * 2048 + tid * 8);
    __syncthreads();
    short8 af[4][2], bf[4][2];
#pragma unroll
    for (int mt = 0; mt < 4; ++mt)
#pragma unroll
      for (int kc = 0; kc < 2; ++kc)
        af[mt][kc] = *(const short8*)(Als + ab[kc] + mt * 1024);
#pragma unroll
    for (int nt = 0; nt < 4; ++nt)
#pragma unroll
      for (int kc = 0; kc < 2; ++kc)
        bf[nt][kc] = *(const short8*)(Bls + bb[kc] + nt * 1024);
#pragma unroll
    for (int kc = 0; kc < 2; ++kc)
#pragma unroll
      for (int mt = 0; mt < 4; ++mt)
#pragma unroll
        for (int nt = 0; nt < 4; ++nt)
          acc[mt][nt] = MFMA16(af[mt][kc], bf[nt][kc], acc[mt][nt]);
    __syncthreads();
  }

  float bias[4];
#pragma unroll
  for (int nt = 0; nt < 4; ++nt) bias[nt] = bp[n0 + wcol + nt * 16 + l16];
#pragma unroll
  for (int mt = 0; mt < 4; ++mt)
#pragma unroll
    for (int r = 0; r < 4; ++r) {
      int gm = m0 + wrow + mt * 16 + quad * 4 + r;
      size_t base = (size_t)gm * EMBED + n0 + wcol;
#pragma unroll
      for (int nt = 0; nt < 4; ++nt) {
        size_t idx = base + nt * 16 + l16;
        X[idx] = acc[mt][nt][r] + bias[nt] + hid[idx];
      }
    }
}

// ---------------- in-place LayerNorm over E=1024, one block per row ----------------
__global__ __launch_bounds__(256) void k_ln(float* __restrict__ x,
                                            const float* __restrict__ gamma,
                                            const float* __restrict__ beta) {
  int row = blockIdx.x, tid = threadIdx.x;
  float4* rp = (float4*)(x + (size_t)row * EMBED);
  float4 v = rp[tid];
  float s = v.x + v.y + v.z + v.w;
  float q = v.x * v.x + v.y * v.y + v.z * v.z + v.w * v.w;
#pragma unroll
  for (int off = 1; off < 64; off <<= 1) {
    s += __shfl_xor(s, off);
    q += __shfl_xor(q, off);
  }
  __shared__ float ss[4], sq[4];
  int w = tid >> 6;
  if ((tid & 63) == 0) { ss[w] = s; sq[w] = q; }
  __syncthreads();
  s = ss[0] + ss[1] + ss[2] + ss[3];
  q = sq[0] + sq[1] + sq[2] + sq[3];
  float mean = s * (1.f / 1024.f);
  float var = q * (1.f / 1024.f) - mean * mean;
  float rstd = rsqrtf(var + 1e-8f);
  float4 g = ((const float4*)gamma)[tid];
  float4 be = ((const float4*)beta)[tid];
  v.x = (v.x - mean) * rstd * g.x + be.x;
  v.y = (v.y - mean) * rstd * g.y + be.y;
  v.z = (v.z - mean) * rstd * g.z + be.z;
  v.w = (v.w - mean) * rstd * g.w + be.w;
  rp[tid] = v;
}

extern "C" void kernel_launch(void* const* d_in, const int* in_sizes, int n_in,
                              void* d_out, int out_size, void* d_ws, size_t ws_size,
                              hipStream_t stream) {
  const float* hid   = (const float*)d_in[0];
  const float* Wq    = (const float*)d_in[1];
  const float* bq    = (const float*)d_in[2];
  const float* Wk    = (const float*)d_in[3];
  const float* bk    = (const float*)d_in[4];
  const float* Wv    = (const float*)d_in[5];
  const float* bv    = (const float*)d_in[6];
  const float* Wp    = (const float*)d_in[7];
  const float* bp    = (const float*)d_in[8];
  const float* gamma = (const float*)d_in[9];
  const float* beta  = (const float*)d_in[10];
  float* out = (float*)d_out;

  char* ws = (char*)d_ws;
  unsigned short* hidA = (unsigned short*)ws;                          // 16 MB  [8192][1024]
  unsigned short* WT   = (unsigned short*)(ws + (size_t)(16 << 20));   //  8 MB  [4096][1024]
  unsigned short* QKV  = (unsigned short*)(ws + (size_t)(24 << 20));   // 48 MB  [8192][3072] (V third unused)
  unsigned short* VT   = (unsigned short*)(ws + (size_t)(72 << 20));   // 16 MB  [64][64][2048]
  unsigned short* CTX  = (unsigned short*)(ws + (size_t)(88 << 20));   // 16 MB  [8192][1024]

  k_prep<<<5120, 256, 0, stream>>>(hid, hidA, Wq, Wk, Wv, Wp, WT);
  k_gemm_qkv<<<dim3(64, 24), 256, 0, stream>>>(hidA, WT, bq, bk, bv, QKV, VT);
  k_attn<<<dim3(64, 16), 128, 0, stream>>>(QKV, VT, CTX);
  k_gemm_proj<<<dim3(64, 8), 256, 0, stream>>>(CTX, WT + (size_t)3 * EMBED * EMBED, bp, hid, out);
  k_ln<<<8192, 256, 0, stream>>>(out, gamma, beta);
}

// Round 8
// 277.988 us; speedup vs baseline: 1.0327x; 1.0327x over previous
//
#include <hip/hip_runtime.h>

#define EMBED 1024
#define SEQ   2048
#define BATCH 4
#define HEADS 16

typedef __attribute__((ext_vector_type(8))) short short8;   // 8 bf16 in 4 VGPRs
typedef __attribute__((ext_vector_type(4))) float floatx4;
typedef __attribute__((ext_vector_type(16))) float floatx16;

#define MFMA16(a, b, c) __builtin_amdgcn_mfma_f32_16x16x32_bf16((a), (b), (c), 0, 0, 0)
#define MFMA32(a, b, c) __builtin_amdgcn_mfma_f32_32x32x16_bf16((a), (b), (c), 0, 0, 0)
#define ATT_SCALE (0.125f * 1.44269504088896340736f)   // 1/sqrt(64) * log2(e), folded into Q

static __device__ __forceinline__ unsigned short f2bf(float f) {
  union { float f; unsigned int u; } v; v.f = f;
  unsigned int u = v.u;
  u += 0x7fffu + ((u >> 16) & 1u);       // RNE
  return (unsigned short)(u >> 16);
}

// v_cvt_pk_bf16_f32: dst.lo16 = bf16(lo), dst.hi16 = bf16(hi)  (RNE)
static __device__ __forceinline__ unsigned cvtpk(float lo, float hi) {
  unsigned r;
  asm("v_cvt_pk_bf16_f32 %0, %1, %2" : "=v"(r) : "v"(lo), "v"(hi));
  return r;
}

static __device__ __forceinline__ void async16(const unsigned short* g, unsigned short* l) {
  __builtin_amdgcn_global_load_lds(
      (const __attribute__((address_space(1))) void*)g,
      (__attribute__((address_space(3))) void*)l, 16, 0, 0);
}

// ---------------- fused prep: hidden fp32->bf16 (blocks 0..4095) +
//                  W[k][n]->WT[n][k] bf16 for Wq,Wk,Wv,Wp (blocks 4096..5119) ---
__global__ __launch_bounds__(256) void k_prep(const float* __restrict__ hid,
                                              unsigned short* __restrict__ hidA,
                                              const float* __restrict__ Wq, const float* __restrict__ Wk,
                                              const float* __restrict__ Wv, const float* __restrict__ Wp,
                                              unsigned short* __restrict__ WT) {
  __shared__ unsigned short tile[64][65];
  const int bid = blockIdx.x, tid = threadIdx.x;
  if (bid < 4096) {                       // cvt: 8 floats / thread
    int i = bid * 256 + tid;
    const float4* s = (const float4*)hid;
    float4 a = s[i * 2], b = s[i * 2 + 1];
    uint4 o;
    o.x = (unsigned)f2bf(a.x) | ((unsigned)f2bf(a.y) << 16);
    o.y = (unsigned)f2bf(a.z) | ((unsigned)f2bf(a.w) << 16);
    o.z = (unsigned)f2bf(b.x) | ((unsigned)f2bf(b.y) << 16);
    o.w = (unsigned)f2bf(b.z) | ((unsigned)f2bf(b.w) << 16);
    ((uint4*)hidA)[i] = o;
    return;
  }
  const int idx = bid - 4096;
  const int z = idx >> 8, rem = idx & 255;
  const float* src = (z == 0) ? Wq : (z == 1) ? Wk : (z == 2) ? Wv : Wp;
  unsigned short* dst = WT + (size_t)z * EMBED * EMBED;
  const int k0 = (rem & 15) * 64, n0 = (rem >> 4) * 64;
  for (int i = tid; i < 4096; i += 256) {
    int r = i >> 6, c = i & 63;
    tile[c][r] = f2bf(src[(size_t)(k0 + r) * EMBED + n0 + c]);
  }
  __syncthreads();
  for (int i = tid; i < 4096; i += 256) {
    int r = i >> 6, c = i & 63;
    dst[(size_t)(n0 + r) * EMBED + k0 + c] = tile[r][c];
  }
}

// ---------------- QKV GEMM (128x128, proven structure) + fused V-transpose ----
// by < 16 : C[m][n0..] = hidA[m,:].WT_qk[n,:] + bias  (Q cols pre-scaled)
// by >= 16: V^T by operand symmetry (rows = d, cols = l); writes VT directly.
__global__ __launch_bounds__(256) void k_gemm_qkv(const unsigned short* __restrict__ A,
                                                  const unsigned short* __restrict__ BT,
                                                  const float* __restrict__ bq,
                                                  const float* __restrict__ bk,
                                                  const float* __restrict__ bv,
                                                  unsigned short* __restrict__ C,
                                                  unsigned short* __restrict__ VT) {
  __shared__ unsigned short Als[128 * 64];
  __shared__ unsigned short Bls[128 * 64];
  const int tid = threadIdx.x;
  const int by = blockIdx.y;
  const bool vmode = (by >= 16);
  const int arow0 = vmode ? (by - 16) * 128 : blockIdx.x * 128;
  const int brow0 = vmode ? blockIdx.x * 128 : by * 128;
  const int w = tid >> 6, lane = tid & 63, l16 = lane & 15, quad = lane >> 4;
  const int l7 = l16 & 7;
  const int wrow = (w >> 1) * 64, wcol = (w & 1) * 64;

  floatx4 acc[4][4];
#pragma unroll
  for (int i = 0; i < 4; ++i)
#pragma unroll
    for (int j = 0; j < 4; ++j) acc[i][j] = {0.f, 0.f, 0.f, 0.f};

  const int srow = tid >> 3;
  const int scol = (((tid & 7) ^ (srow & 7)) * 8);
  const unsigned short* Arow = vmode ? (BT + (size_t)2 * EMBED * EMBED) : A;
  const unsigned short* Brow = vmode ? A : BT;
  const unsigned short* Ap = Arow + (size_t)(arow0 + srow) * EMBED + scol;
  const unsigned short* Bp = Brow + (size_t)(brow0 + srow) * EMBED + scol;

  int ab[2], bb[2];
#pragma unroll
  for (int kc = 0; kc < 2; ++kc) {
    ab[kc] = (wrow + l16) * 64 + (((4 * kc + quad) ^ l7) << 3);
    bb[kc] = (wcol + l16) * 64 + (((4 * kc + quad) ^ l7) << 3);
  }

  for (int kt = 0; kt < 16; ++kt) {
    const int k0 = kt * 64;
#pragma unroll
    for (int i = 0; i < 4; ++i)
      async16(Ap + k0 + (size_t)i * 32 * EMBED, Als + i * 2048 + tid * 8);
#pragma unroll
    for (int i = 0; i < 4; ++i)
      async16(Bp + k0 + (size_t)i * 32 * EMBED, Bls + i * 2048 + tid * 8);
    __syncthreads();
    short8 af[4][2], bf[4][2];
#pragma unroll
    for (int mt = 0; mt < 4; ++mt)
#pragma unroll
      for (int kc = 0; kc < 2; ++kc)
        af[mt][kc] = *(const short8*)(Als + ab[kc] + mt * 1024);
#pragma unroll
    for (int nt = 0; nt < 4; ++nt)
#pragma unroll
      for (int kc = 0; kc < 2; ++kc)
        bf[nt][kc] = *(const short8*)(Bls + bb[kc] + nt * 1024);
#pragma unroll
    for (int kc = 0; kc < 2; ++kc)
#pragma unroll
      for (int mt = 0; mt < 4; ++mt)
#pragma unroll
        for (int nt = 0; nt < 4; ++nt)
          acc[mt][nt] = MFMA16(af[mt][kc], bf[nt][kc], acc[mt][nt]);
    __syncthreads();
  }

  if (!vmode) {
    const int n0 = brow0;
    const float* bsel = (n0 < 1024) ? bq : bk;
    const float scl = (n0 < 1024) ? ATT_SCALE : 1.0f;
    const int nb = n0 & 1023;
    float bias[4];
#pragma unroll
    for (int nt = 0; nt < 4; ++nt) bias[nt] = bsel[nb + wcol + nt * 16 + l16];
#pragma unroll
    for (int mt = 0; mt < 4; ++mt)
#pragma unroll
      for (int r = 0; r < 4; ++r) {
        int gm = arow0 + wrow + mt * 16 + quad * 4 + r;
        size_t base = (size_t)gm * 3072 + n0 + wcol;
#pragma unroll
        for (int nt = 0; nt < 4; ++nt)
          C[base + nt * 16 + l16] = f2bf((acc[mt][nt][r] + bias[nt]) * scl);
      }
  } else {
    // rows = d-global, cols = l-global; VT[(b*16+h)*64 + d][l]
#pragma unroll
    for (int mt = 0; mt < 4; ++mt)
#pragma unroll
      for (int r = 0; r < 4; ++r) {
        const int drow = arow0 + wrow + mt * 16 + quad * 4 + r;   // 0..1023
        const float bias = bv[drow];
        const int cg0 = brow0 + wcol;                             // col base (l-global)
        const int b = cg0 >> 11;                                  // constant per block
        const size_t base = ((size_t)((b * 16 + (drow >> 6)) * 64 + (drow & 63))) * SEQ
                            + (cg0 & 2047);
#pragma unroll
        for (int nt = 0; nt < 4; ++nt)
          VT[base + nt * 16 + l16] = f2bf(acc[mt][nt][r] + bias);
      }
  }
}

// QK step: S[kvg][qg] = K-tile(LDS) x Q(frags), swapped-operand 32x32
static __device__ __forceinline__ void qk_step(const unsigned short* Kc,
                                               const short8 qf[2][4],
                                               int l32, int hi,
                                               floatx16 S[2][2]) {
#pragma unroll
  for (int kvg = 0; kvg < 2; ++kvg) {
    short8 kf[4];
#pragma unroll
    for (int ds = 0; ds < 4; ++ds) {
      const int row = kvg * 32 + l32;
      kf[ds] = *(const short8*)(Kc + row * 64 + (((ds * 2 + hi) ^ (row & 7)) << 3));
    }
#pragma unroll
    for (int qg = 0; qg < 2; ++qg) {
      floatx16 s;
#pragma unroll
      for (int c = 0; c < 16; ++c) s[c] = 0.f;
#pragma unroll
      for (int ds = 0; ds < 4; ++ds) s = MFMA32(kf[ds], qf[qg][ds], s);
      S[kvg][qg] = s;
    }
  }
}

// ---------------- attention v14: v10 + software-pipelined S (T15) -------------
// Iteration kt: exp2/pack(S of tile kt) -> PV(tile kt) -> QK(tile kt+1 -> S).
// QK of kt+1 has no data dep on exp2/pack/PV of kt (only WAR on S after exp2's
// reads), so its 16 MFMA interleave with pack's VALU, and the MFMA pipe sees
// PV+QK nearly back-to-back instead of being split by the exp2 phase.
// Buffers: K staged TWO ahead (K[kt+2]->Kls[kt&1]), V one ahead
// (V[kt+1]->Vls[(kt+1)&1]); same-iter stage/read buffers disjoint:
//   read V from Vls[kt&1], K from Kls[(kt+1)&1].  Extra prologue barrier
// protects Kls[0] between prologue QK(tile0) and kt=0's K[2] stage.
// Per-tile math order unchanged -> bit-identical output.  S persists across
// iters (+64 VGPR, ~200 total <= 256 @ 2 waves/SIMD).
__global__ __launch_bounds__(256, 2) void k_attn(const unsigned short* __restrict__ QKV,
                                                 const unsigned short* __restrict__ VT,
                                                 unsigned short* __restrict__ CTX) {
  const int bh = blockIdx.x, qt = blockIdx.y;
  const int b = bh >> 4, h = bh & 15;
  const int tid = threadIdx.x;
  const int w = tid >> 6, lane = tid & 63;
  const int l32 = lane & 31, hi = lane >> 5;

  __shared__ unsigned short Kls[2][64 * 64];   // [buf][kv][d]  xor-chunk swizzled
  __shared__ unsigned short Vls[2][64 * 64];   // [buf][d][kv]  xor-chunk swizzled
  __shared__ float rsls[4][64];                // per-wave row sums

  const unsigned short* Qb = QKV + (size_t)(b * SEQ + qt * 256 + w * 64) * 3072 + h * 64;
  const unsigned short* Kb = QKV + (size_t)(b * SEQ) * 3072 + 1024 + h * 64;
  const unsigned short* Vb = VT + (size_t)bh * 64 * SEQ;

  // Q fragments (B-operand of swapped QK): qf[qg][ds] holds
  // Q[q = qg*32 + l32][d = ds*16 + hi*8 + j]  (pre-scaled by ATT_SCALE)
  short8 qf[2][4];
#pragma unroll
  for (int qg = 0; qg < 2; ++qg)
#pragma unroll
    for (int ds = 0; ds < 4; ++ds)
      qf[qg][ds] = *(const short8*)(Qb + (size_t)(qg * 32 + l32) * 3072 + ds * 16 + hi * 8);

  floatx16 o[2][2];
  floatx16 S[2][2];
  float rs[2] = {0.f, 0.f};
#pragma unroll
  for (int qg = 0; qg < 2; ++qg)
#pragma unroll
    for (int dg = 0; dg < 2; ++dg)
#pragma unroll
      for (int c = 0; c < 16; ++c) o[qg][dg][c] = 0.f;

  const int srow = tid >> 3;                              // 0..31
  const int scol = (((tid & 7) ^ (srow & 7)) * 8);        // swizzled source chunk

  // prologue: stage K[0],V[0] -> buf0, K[1] -> buf1
  async16(Kb + (size_t)srow * 3072 + scol, Kls[0] + tid * 8);
  async16(Kb + (size_t)(32 + srow) * 3072 + scol, Kls[0] + 2048 + tid * 8);
  async16(Vb + (size_t)srow * SEQ + scol, Vls[0] + tid * 8);
  async16(Vb + (size_t)(32 + srow) * SEQ + scol, Vls[0] + 2048 + tid * 8);
  async16(Kb + (size_t)(64 + srow) * 3072 + scol, Kls[1] + tid * 8);
  async16(Kb + (size_t)(64 + 32 + srow) * 3072 + scol, Kls[1] + 2048 + tid * 8);
  __syncthreads();

  // QK tile 0 -> S (reads Kls[0])
  qk_step(Kls[0], qf, l32, hi, S);
  __syncthreads();   // all waves done with Kls[0] before kt=0 stages K[2] there

  for (int kt = 0; kt < 32; ++kt) {
    const int cur = kt & 1;
    // stage V[kt+1] -> Vls[cur^1]  (PV this iter reads Vls[cur])
    if (kt < 31) {
      const int vn = (kt + 1) * 64;
      unsigned short* Vd = Vls[cur ^ 1];
      async16(Vb + (size_t)srow * SEQ + vn + scol, Vd + tid * 8);
      async16(Vb + (size_t)(32 + srow) * SEQ + vn + scol, Vd + 2048 + tid * 8);
    }
    // stage K[kt+2] -> Kls[cur]  (QK this iter reads Kls[cur^1]; K[kt] in
    // Kls[cur] was last read in iter kt-1, protected by its end barrier)
    if (kt < 30) {
      const int kn = (kt + 2) * 64;
      unsigned short* Kd = Kls[cur];
      async16(Kb + (size_t)(kn + srow) * 3072 + scol, Kd + tid * 8);
      async16(Kb + (size_t)(kn + 32 + srow) * 3072 + scol, Kd + 2048 + tid * 8);
    }

    // exp2 + pack of tile kt (reads S; independent of this iter's QK below)
    short8 pa[2][4];   // [qg][ks] packed P fragments (PV A-operand)
#pragma unroll
    for (int kvg = 0; kvg < 2; ++kvg)
#pragma unroll
      for (int qg = 0; qg < 2; ++qg) {
        float p[16];
#pragma unroll
        for (int c = 0; c < 16; ++c) p[c] = __builtin_amdgcn_exp2f(S[kvg][qg][c]);
        rs[qg] += (((p[0] + p[1]) + (p[2] + p[3])) + ((p[4] + p[5]) + (p[6] + p[7])))
                + (((p[8] + p[9]) + (p[10] + p[11])) + ((p[12] + p[13]) + (p[14] + p[15])));
#pragma unroll
        for (int half = 0; half < 2; ++half) {   // ks = kvg*2 + half
          unsigned w0 = cvtpk(p[half * 8 + 0], p[half * 8 + 1]);
          unsigned w1 = cvtpk(p[half * 8 + 2], p[half * 8 + 3]);
          unsigned w2 = cvtpk(p[half * 8 + 4], p[half * 8 + 5]);
          unsigned w3 = cvtpk(p[half * 8 + 6], p[half * 8 + 7]);
          asm("v_permlane32_swap_b32 %0, %1" : "+v"(w0), "+v"(w2));
          asm("v_permlane32_swap_b32 %0, %1" : "+v"(w1), "+v"(w3));
          union { unsigned u[4]; short8 s8; } pk;
          pk.u[0] = w0; pk.u[1] = w1; pk.u[2] = w2; pk.u[3] = w3;
          pa[qg][kvg * 2 + half] = pk.s8;
        }
      }

    // O += P V   (V[kt] in Vls[cur])
#pragma unroll
    for (int dg = 0; dg < 2; ++dg) {
      short8 vf[4];
#pragma unroll
      for (int ks = 0; ks < 4; ++ks) {
        const int row = dg * 32 + l32;
        vf[ks] = *(const short8*)(Vls[cur] + row * 64 + (((ks * 2 + hi) ^ (row & 7)) << 3));
      }
#pragma unroll
      for (int qg = 0; qg < 2; ++qg)
#pragma unroll
        for (int ks = 0; ks < 4; ++ks)
          o[qg][dg] = MFMA32(pa[qg][ks], vf[ks], o[qg][dg]);
    }

    // QK tile kt+1 -> S  (K[kt+1] in Kls[cur^1]; overlaps pack/PV above)
    if (kt < 31) qk_step(Kls[cur ^ 1], qf, l32, hi, S);

    // single barrier: drains this iter's stages (ready next iter) and
    // protects the buffers staged next iter from in-flight readers
    __syncthreads();
  }

  // lanes l and l+32 hold the same q; combine, publish per-q sums via LDS
  rs[0] += __shfl_xor(rs[0], 32);
  rs[1] += __shfl_xor(rs[1], 32);
  if (lane < 32) {
    rsls[w][l32] = rs[0];
    rsls[w][32 + l32] = rs[1];
  }
  // same-wave LDS readback; per-wave in-order, compiler inserts the lgkm wait

  // write ctx[b*SEQ + q][h*64 + d] bf16; O rows: q = (j&3)+8*(j>>2)+4*hi (+32qg)
#pragma unroll
  for (int qg = 0; qg < 2; ++qg)
#pragma unroll
    for (int j = 0; j < 16; ++j) {
      const int rl = (j & 3) + 8 * (j >> 2) + 4 * hi;
      const float inv = 1.f / rsls[w][qg * 32 + rl];
      const int gq = b * SEQ + qt * 256 + w * 64 + qg * 32 + rl;
      const size_t base = (size_t)gq * EMBED + h * 64;
#pragma unroll
      for (int dg = 0; dg < 2; ++dg)
        CTX[base + dg * 32 + l32] = f2bf(o[qg][dg][j] * inv);
    }
}

// ---------------- proj GEMM + bias + residual -> fp32 x ----------------
__global__ __launch_bounds__(256) void k_gemm_proj(const unsigned short* __restrict__ A,
                                                   const unsigned short* __restrict__ BT,
                                                   const float* __restrict__ bp,
                                                   const float* __restrict__ hid,
                                                   float* __restrict__ X) {
  __shared__ unsigned short Als[128 * 64];
  __shared__ unsigned short Bls[128 * 64];
  const int tid = threadIdx.x;
  const int m0 = blockIdx.x * 128, n0 = blockIdx.y * 128;
  const int w = tid >> 6, lane = tid & 63, l16 = lane & 15, quad = lane >> 4;
  const int l7 = l16 & 7;
  const int wrow = (w >> 1) * 64, wcol = (w & 1) * 64;

  floatx4 acc[4][4];
#pragma unroll
  for (int i = 0; i < 4; ++i)
#pragma unroll
    for (int j = 0; j < 4; ++j) acc[i][j] = {0.f, 0.f, 0.f, 0.f};

  const int srow = tid >> 3;
  const int scol = (((tid & 7) ^ (srow & 7)) * 8);
  const unsigned short* Ap = A + (size_t)(m0 + srow) * EMBED + scol;
  const unsigned short* Bp = BT + (size_t)(n0 + srow) * EMBED + scol;

  int ab[2], bb[2];
#pragma unroll
  for (int kc = 0; kc < 2; ++kc) {
    ab[kc] = (wrow + l16) * 64 + (((4 * kc + quad) ^ l7) << 3);
    bb[kc] = (wcol + l16) * 64 + (((4 * kc + quad) ^ l7) << 3);
  }

  for (int kt = 0; kt < 16; ++kt) {
    const int k0 = kt * 64;
#pragma unroll
    for (int i = 0; i < 4; ++i)
      async16(Ap + k0 + (size_t)i * 32 * EMBED, Als + i * 2048 + tid * 8);
#pragma unroll
    for (int i = 0; i < 4; ++i)
      async16(Bp + k0 + (size_t)i * 32 * EMBED, Bls + i * 2048 + tid * 8);
    __syncthreads();
    short8 af[4][2], bf[4][2];
#pragma unroll
    for (int mt = 0; mt < 4; ++mt)
#pragma unroll
      for (int kc = 0; kc < 2; ++kc)
        af[mt][kc] = *(const short8*)(Als + ab[kc] + mt * 1024);
#pragma unroll
    for (int nt = 0; nt < 4; ++nt)
#pragma unroll
      for (int kc = 0; kc < 2; ++kc)
        bf[nt][kc] = *(const short8*)(Bls + bb[kc] + nt * 1024);
#pragma unroll
    for (int kc = 0; kc < 2; ++kc)
#pragma unroll
      for (int mt = 0; mt < 4; ++mt)
#pragma unroll
        for (int nt = 0; nt < 4; ++nt)
          acc[mt][nt] = MFMA16(af[mt][kc], bf[nt][kc], acc[mt][nt]);
    __syncthreads();
  }

  float bias[4];
#pragma unroll
  for (int nt = 0; nt < 4; ++nt) bias[nt] = bp[n0 + wcol + nt * 16 + l16];
#pragma unroll
  for (int mt = 0; mt < 4; ++mt)
#pragma unroll
    for (int r = 0; r < 4; ++r) {
      int gm = m0 + wrow + mt * 16 + quad * 4 + r;
      size_t base = (size_t)gm * EMBED + n0 + wcol;
#pragma unroll
      for (int nt = 0; nt < 4; ++nt) {
        size_t idx = base + nt * 16 + l16;
        X[idx] = acc[mt][nt][r] + bias[nt] + hid[idx];
      }
    }
}

// ---------------- in-place LayerNorm over E=1024, one block per row ----------------
__global__ __launch_bounds__(256) void k_ln(float* __restrict__ x,
                                            const float* __restrict__ gamma,
                                            const float* __restrict__ beta) {
  int row = blockIdx.x, tid = threadIdx.x;
  float4* rp = (float4*)(x + (size_t)row * EMBED);
  float4 v = rp[tid];
  float s = v.x + v.y + v.z + v.w;
  float q = v.x * v.x + v.y * v.y + v.z * v.z + v.w * v.w;
#pragma unroll
  for (int off = 1; off < 64; off <<= 1) {
    s += __shfl_xor(s, off);
    q += __shfl_xor(q, off);
  }
  __shared__ float ss[4], sq[4];
  int w = tid >> 6;
  if ((tid & 63) == 0) { ss[w] = s; sq[w] = q; }
  __syncthreads();
  s = ss[0] + ss[1] + ss[2] + ss[3];
  q = sq[0] + sq[1] + sq[2] + sq[3];
  float mean = s * (1.f / 1024.f);
  float var = q * (1.f / 1024.f) - mean * mean;
  float rstd = rsqrtf(var + 1e-8f);
  float4 g = ((const float4*)gamma)[tid];
  float4 be = ((const float4*)beta)[tid];
  v.x = (v.x - mean) * rstd * g.x + be.x;
  v.y = (v.y - mean) * rstd * g.y + be.y;
  v.z = (v.z - mean) * rstd * g.z + be.z;
  v.w = (v.w - mean) * rstd * g.w + be.w;
  rp[tid] = v;
}

extern "C" void kernel_launch(void* const* d_in, const int* in_sizes, int n_in,
                              void* d_out, int out_size, void* d_ws, size_t ws_size,
                              hipStream_t stream) {
  const float* hid   = (const float*)d_in[0];
  const float* Wq    = (const float*)d_in[1];
  const float* bq    = (const float*)d_in[2];
  const float* Wk    = (const float*)d_in[3];
  const float* bk    = (const float*)d_in[4];
  const float* Wv    = (const float*)d_in[5];
  const float* bv    = (const float*)d_in[6];
  const float* Wp    = (const float*)d_in[7];
  const float* bp    = (const float*)d_in[8];
  const float* gamma = (const float*)d_in[9];
  const float* beta  = (const float*)d_in[10];
  float* out = (float*)d_out;

  char* ws = (char*)d_ws;
  unsigned short* hidA = (unsigned short*)ws;                          // 16 MB  [8192][1024]
  unsigned short* WT   = (unsigned short*)(ws + (size_t)(16 << 20));   //  8 MB  [4096][1024]
  unsigned short* QKV  = (unsigned short*)(ws + (size_t)(24 << 20));   // 48 MB  [8192][3072] (V third unused)
  unsigned short* VT   = (unsigned short*)(ws + (size_t)(72 << 20));   // 16 MB  [64][64][2048]
  unsigned short* CTX  = (unsigned short*)(ws + (size_t)(88 << 20));   // 16 MB  [8192][1024]

  k_prep<<<5120, 256, 0, stream>>>(hid, hidA, Wq, Wk, Wv, Wp, WT);
  k_gemm_qkv<<<dim3(64, 24), 256, 0, stream>>>(hidA, WT, bq, bk, bv, QKV, VT);
  k_attn<<<dim3(64, 8), 256, 0, stream>>>(QKV, VT, CTX);
  k_gemm_proj<<<dim3(64, 8), 256, 0, stream>>>(CTX, WT + (size_t)3 * EMBED * EMBED, bp, hid, out);
  k_ln<<<8192, 256, 0, stream>>>(out, gamma, beta);
}